// Round 17
// baseline (311.551 us; speedup 1.0000x reference)
//
#include <hip/hip_runtime.h>

#define N_ROWS 16384
#define DIM 256
#define MARGINF 0.3f
#define CH 1024
#define NT 64            // 16-col tiles per chunk
#define LOG2E 1.44269504089f

typedef float f32x4 __attribute__((ext_vector_type(4)));
typedef int i32x8 __attribute__((ext_vector_type(8)));

__device__ __forceinline__ float fexp2(float x) {
#if __has_builtin(__builtin_amdgcn_exp2f)
  return __builtin_amdgcn_exp2f(x);
#else
  return exp2f(x);
#endif
}

// ------------------------------------------------------------------
// float -> OCP e4m3fn (manual fallback)
// ------------------------------------------------------------------
__device__ __forceinline__ unsigned char to_e4m3(float f) {
  unsigned u = __float_as_uint(f);
  unsigned sign = (u >> 24) & 0x80u;
  float a = fabsf(f);
  if (a >= 448.0f) return (unsigned char)(sign | 0x7eu);
  if (a < 0.015625f) {
    int q = (int)(a * 512.0f + 0.5f);
    return (unsigned char)(sign | (unsigned)q);
  }
  int e;
  float m = frexpf(a, &e);
  float mant = 2.0f * m;
  int e8 = e - 1;
  int mb = (int)(mant * 8.0f + 0.5f) - 8;
  if (mb == 8) { mb = 0; ++e8; if (e8 > 8) return (unsigned char)(sign | 0x7eu); }
  return (unsigned char)(sign | (unsigned)((e8 + 7) << 3) | (unsigned)mb);
}

__device__ __forceinline__ unsigned int pack4_e4m3(float a, float b, float c, float d) {
#if __has_builtin(__builtin_amdgcn_cvt_pk_fp8_f32)
  int lo = __builtin_amdgcn_cvt_pk_fp8_f32(a, b, 0, false);
  int r = __builtin_amdgcn_cvt_pk_fp8_f32(c, d, lo, true);
  return (unsigned int)r;
#else
  return (unsigned int)to_e4m3(a) | ((unsigned int)to_e4m3(b) << 8) |
         ((unsigned int)to_e4m3(c) << 16) | ((unsigned int)to_e4m3(d) << 24);
#endif
}

// ------------------------------------------------------------------
// Kernel 1: norms + exact fp32 diag cosine + fp8 outputs.
// x: row-major xn8 (A-side, log2e-folded). y: FRAGMENT-MAJOR ybf
// (MFMA B-operand lane order; GEMM B load = base + lane*32, fully
// coalesced). [verbatim R15 - passed]
// ------------------------------------------------------------------
__global__ __launch_bounds__(256) void normalize_kernel(
    const float* __restrict__ x, const float* __restrict__ y,
    unsigned int* __restrict__ xn8, unsigned char* __restrict__ ybf,
    float* __restrict__ diagF) {
  const int wid = threadIdx.x >> 6;
  const int lane = threadIdx.x & 63;
  const int r = blockIdx.x * 4 + wid;  // 0..16383
  const float4 vx = *reinterpret_cast<const float4*>(x + (size_t)r * DIM + lane * 4);
  const float4 vy = *reinterpret_cast<const float4*>(y + (size_t)r * DIM + lane * 4);
  float sx = vx.x * vx.x + vx.y * vx.y + vx.z * vx.z + vx.w * vx.w;
  float sy = vy.x * vy.x + vy.y * vy.y + vy.z * vy.z + vy.w * vy.w;
  float sxy = vx.x * vy.x + vx.y * vy.y + vx.z * vy.z + vx.w * vy.w;
  #pragma unroll
  for (int off = 32; off; off >>= 1) {
    sx += __shfl_xor(sx, off);
    sy += __shfl_xor(sy, off);
    sxy += __shfl_xor(sxy, off);
  }
  const float scx = LOG2E / fmaxf(sqrtf(sx), 1e-8f);   // log2e folded into A
  const float scy = 1.0f / fmaxf(sqrtf(sy), 1e-8f);
  if (lane == 0) diagF[r] = sxy * (scx / LOG2E) * scy;
  xn8[(size_t)r * 64 + lane] = pack4_e4m3(vx.x * scx, vx.y * scx, vx.z * scx, vx.w * scx);
  // y fragment-major: this lane's 4 bytes cover k = [4*lane, 4*lane+4)
  const unsigned int py = pack4_e4m3(vy.x * scy, vy.y * scy, vy.z * scy, vy.w * scy);
  const int t2 = (r >> 4) * 2 + (lane >> 5);             // global tile*2 + kb
  const int fl = ((lane >> 3) & 3) * 16 + (r & 15);      // fragment lane
  const unsigned dst = (unsigned)t2 * 2048 + (unsigned)fl * 32 + (lane & 7) * 4;
  *reinterpret_cast<unsigned int*>(ybf + dst) = py;
}

// ------------------------------------------------------------------
// Kernel 2: barrier-free, LDS-free MX-fp8 GEMM + exp2, with
// register-double-buffered B (unroll-2 ping-pong, named bufs).
// Wave = 64-row band x 1024-col chunk [R15 geometry]. Loads for
// tile t+1 issue BEFORE the MFMA convoy of tile t -> ~500 cyc of
// MFMA+epilogue covers L2 latency. Zero LDS, zero barriers.
// ------------------------------------------------------------------
__global__ __launch_bounds__(256, 4) void gemm_exp_kernel(
    const unsigned char* __restrict__ xn8, const unsigned char* __restrict__ ybf,
    float* __restrict__ rowpart, float* __restrict__ colpartW,
    float* __restrict__ rowsumG, float* __restrict__ colsumG, int use_scratch) {
  const int tid = threadIdx.x;
  const int lane = tid & 63;
  const int wid = tid >> 6;
  const int grp = lane >> 4, li = lane & 15;

  const int bid = blockIdx.x;                // 0..1023
  const int xcd = bid & 7;
  const int rest = bid >> 3;                 // 0..127
  const int chunk = xcd * 2 + (rest >> 6);   // 0..15 (2 chunks/XCD -> L2)
  const int band = ((rest & 63) << 2) + wid; // 0..255 (64-row band per wave)
  const int rowBase = band * 64;
  const int colBase = chunk * CH;

  // ---- A: 64 rows x 256 K fp8 -> a[4][2] i32x8 (64 VGPR) ----
  i32x8 a[4][2];
  #pragma unroll
  for (int m = 0; m < 4; ++m)
    #pragma unroll
    for (int kb = 0; kb < 2; ++kb) {
      const int row = rowBase + m * 16 + li;
      a[m][kb] = *reinterpret_cast<const i32x8*>(
          xn8 + (size_t)row * DIM + kb * 128 + grp * 32);
    }

  f32x4 rsum4[4];
  #pragma unroll
  for (int m = 0; m < 4; ++m) rsum4[m] = (f32x4)(0.0f);

  const f32x4 z4 = (f32x4)(0.0f);
  // per-lane B pointer: chunk base + lane's 32B fragment slot
  const unsigned char* yb = ybf + (size_t)chunk * (NT * 4096) + (size_t)lane * 32;

  // epilogue for one finished tile (acc in registers)
  auto EPI = [&](int t, f32x4 (&acc)[4]) __attribute__((always_inline)) {
    f32x4 ev[4];
    #pragma unroll
    for (int m = 0; m < 4; ++m) {
      #pragma unroll
      for (int j = 0; j < 4; ++j) ev[m][j] = fexp2(acc[m][j]);
      rsum4[m] += ev[m];
    }
    const f32x4 cst = (ev[0] + ev[1]) + (ev[2] + ev[3]);
    float cs = (cst[0] + cst[1]) + (cst[2] + cst[3]);
    cs += __shfl_xor(cs, 16);
    cs += __shfl_xor(cs, 32);
    if (grp == 0) {
      const int c = colBase + t * 16 + li;
      if (use_scratch) colpartW[(size_t)band * N_ROWS + c] = cs;
      else atomicAdd(&colsumG[c], cs);
    }
  };

  // compute one tile from register B-frags into acc
  auto MFMA8 = [&](const i32x8& b0, const i32x8& b1, f32x4 (&acc)[4])
      __attribute__((always_inline)) {
    __builtin_amdgcn_s_setprio(1);
    #pragma unroll
    for (int m = 0; m < 4; ++m)
      acc[m] = __builtin_amdgcn_mfma_scale_f32_16x16x128_f8f6f4(
          a[m][0], b0, z4, 0, 0, 0, 127, 0, 127);
    #pragma unroll
    for (int m = 0; m < 4; ++m)
      acc[m] = __builtin_amdgcn_mfma_scale_f32_16x16x128_f8f6f4(
          a[m][1], b1, acc[m], 0, 0, 0, 127, 0, 127);
    __builtin_amdgcn_s_setprio(0);
  };

  // ---- unroll-2 ping-pong: prefetch (t+1) before computing t ----
  i32x8 bA0 = *reinterpret_cast<const i32x8*>(yb);
  i32x8 bA1 = *reinterpret_cast<const i32x8*>(yb + 2048);
  i32x8 bB0, bB1;

  for (int t = 0; t < NT; t += 2) {
    // prefetch tile t+1 into B-bufs (always valid: NT even, t+1 < NT)
    bB0 = *reinterpret_cast<const i32x8*>(yb + 4096);
    bB1 = *reinterpret_cast<const i32x8*>(yb + 4096 + 2048);
    {
      f32x4 acc[4];
      MFMA8(bA0, bA1, acc);
      EPI(t, acc);
    }
    // prefetch tile t+2 into A-bufs (guard last pair)
    if (t + 2 < NT) {
      bA0 = *reinterpret_cast<const i32x8*>(yb + 8192);
      bA1 = *reinterpret_cast<const i32x8*>(yb + 8192 + 2048);
    }
    {
      f32x4 acc[4];
      MFMA8(bB0, bB1, acc);
      EPI(t + 1, acc);
    }
    yb += 8192;
  }

  // ---- row sums: wave-exclusive rows, direct write ----
  #pragma unroll
  for (int m = 0; m < 4; ++m) {
    #pragma unroll
    for (int j = 0; j < 4; ++j) {
      float v = rsum4[m][j];
      v += __shfl_xor(v, 1); v += __shfl_xor(v, 2);
      v += __shfl_xor(v, 4); v += __shfl_xor(v, 8);
      if (li == 0) {
        const int r = rowBase + m * 16 + grp * 4 + j;
        if (use_scratch) rowpart[(size_t)chunk * N_ROWS + r] = v;
        else atomicAdd(&rowsumG[r], v);
      }
    }
  }
}

// ------------------------------------------------------------------
// Kernel 3: reduce partials + final loss. [verbatim R15]
// ------------------------------------------------------------------
__global__ __launch_bounds__(256) void finalize_kernel(
    const float* __restrict__ rowpart, const float* __restrict__ colpartW,
    const float* __restrict__ rowsumG, const float* __restrict__ colsumG,
    const float* __restrict__ diagF, float* __restrict__ out, int use_scratch) {
  __shared__ float red[4];
  const int i = blockIdx.x * 256 + threadIdx.x;
  float rs, cs;
  if (use_scratch) {
    rs = 0.0f;
    #pragma unroll
    for (int c = 0; c < 16; ++c) rs += rowpart[(size_t)c * N_ROWS + i];
    cs = 0.0f;
    #pragma unroll 8
    for (int b = 0; b < 256; ++b) cs += colpartW[(size_t)b * N_ROWS + i];
  } else {
    rs = rowsumG[i];
    cs = colsumG[i];
  }
  const float d = diagF[i];
  const float e8 = fexp2(LOG2E * d);          // ~= gemm's exp2(S'_ii)
  const float mm = __expf(d - MARGINF);
  float v = mm / (mm + rs - e8) + mm / (mm + cs - e8);
  #pragma unroll
  for (int off = 32; off; off >>= 1) v += __shfl_xor(v, off);
  if ((threadIdx.x & 63) == 0) red[threadIdx.x >> 6] = v;
  __syncthreads();
  if (threadIdx.x == 0) {
    const float t = red[0] + red[1] + red[2] + red[3];
    atomicAdd(out, -t / (float)N_ROWS);
  }
}

// ------------------------------------------------------------------
extern "C" void kernel_launch(void* const* d_in, const int* in_sizes, int n_in,
                              void* d_out, int out_size, void* d_ws, size_t ws_size,
                              hipStream_t stream) {
  const float* x = (const float*)d_in[0];
  const float* y = (const float*)d_in[1];
  char* ws = (char*)d_ws;
  unsigned char* xn8 = (unsigned char*)ws;                   // 4 MiB
  unsigned char* ybf = (unsigned char*)(ws + (4u << 20));    // 4 MiB (frag-major)
  float* diagF    = (float*)(ws + (8u << 20));               // 64 KiB
  float* rowpart  = (float*)(ws + (8u << 20) + 65536);       // 1 MiB [16][N]
  float* colpartW = (float*)(ws + (8u << 20) + 65536 + (1u << 20));  // 16 MiB [256][N]
  float* rowsumG = rowpart;                                  // fallback aliases
  float* colsumG = rowpart + N_ROWS;
  const size_t need_scratch = (8u << 20) + 65536 + (1u << 20) + (16u << 20);
  const int use_scratch = (ws_size >= need_scratch) ? 1 : 0;

  hipMemsetAsync(d_out, 0, sizeof(float), stream);
  if (!use_scratch) hipMemsetAsync(rowsumG, 0, 2 * N_ROWS * sizeof(float), stream);
  normalize_kernel<<<4096, 256, 0, stream>>>(x, y, (unsigned int*)xn8, ybf, diagF);
  gemm_exp_kernel<<<1024, 256, 0, stream>>>(xn8, ybf, rowpart, colpartW,
                                            rowsumG, colsumG, use_scratch);
  finalize_kernel<<<64, 256, 0, stream>>>(rowpart, colpartW, rowsumG, colsumG,
                                          diagF, (float*)d_out, use_scratch);
}

// Round 18
// 103.710 us; speedup vs baseline: 3.0041x; 3.0041x over previous
//
#include <hip/hip_runtime.h>

#define N_ROWS 16384
#define DIM 256
#define MARGINF 0.3f
#define CH 1024
#define NT 64            // 16-col tiles per chunk
#define LOG2E 1.44269504089f

typedef float f32x4 __attribute__((ext_vector_type(4)));
typedef int i32x8 __attribute__((ext_vector_type(8)));

__device__ __forceinline__ float fexp2(float x) {
#if __has_builtin(__builtin_amdgcn_exp2f)
  return __builtin_amdgcn_exp2f(x);
#else
  return exp2f(x);
#endif
}

// ------------------------------------------------------------------
// float -> OCP e4m3fn (manual fallback)
// ------------------------------------------------------------------
__device__ __forceinline__ unsigned char to_e4m3(float f) {
  unsigned u = __float_as_uint(f);
  unsigned sign = (u >> 24) & 0x80u;
  float a = fabsf(f);
  if (a >= 448.0f) return (unsigned char)(sign | 0x7eu);
  if (a < 0.015625f) {
    int q = (int)(a * 512.0f + 0.5f);
    return (unsigned char)(sign | (unsigned)q);
  }
  int e;
  float m = frexpf(a, &e);
  float mant = 2.0f * m;
  int e8 = e - 1;
  int mb = (int)(mant * 8.0f + 0.5f) - 8;
  if (mb == 8) { mb = 0; ++e8; if (e8 > 8) return (unsigned char)(sign | 0x7eu); }
  return (unsigned char)(sign | (unsigned)((e8 + 7) << 3) | (unsigned)mb);
}

__device__ __forceinline__ unsigned int pack4_e4m3(float a, float b, float c, float d) {
#if __has_builtin(__builtin_amdgcn_cvt_pk_fp8_f32)
  int lo = __builtin_amdgcn_cvt_pk_fp8_f32(a, b, 0, false);
  int r = __builtin_amdgcn_cvt_pk_fp8_f32(c, d, lo, true);
  return (unsigned int)r;
#else
  return (unsigned int)to_e4m3(a) | ((unsigned int)to_e4m3(b) << 8) |
         ((unsigned int)to_e4m3(c) << 16) | ((unsigned int)to_e4m3(d) << 24);
#endif
}

// ------------------------------------------------------------------
// Kernel 1: norms + exact fp32 diag cosine + fp8 outputs.
// x: row-major xn8 (A-side, log2e-folded). y: FRAGMENT-MAJOR ybf
// (MFMA B-operand lane order; GEMM B load = base + lane*32, fully
// coalesced). [verbatim R15 - passed]
// ------------------------------------------------------------------
__global__ __launch_bounds__(256) void normalize_kernel(
    const float* __restrict__ x, const float* __restrict__ y,
    unsigned int* __restrict__ xn8, unsigned char* __restrict__ ybf,
    float* __restrict__ diagF) {
  const int wid = threadIdx.x >> 6;
  const int lane = threadIdx.x & 63;
  const int r = blockIdx.x * 4 + wid;  // 0..16383
  const float4 vx = *reinterpret_cast<const float4*>(x + (size_t)r * DIM + lane * 4);
  const float4 vy = *reinterpret_cast<const float4*>(y + (size_t)r * DIM + lane * 4);
  float sx = vx.x * vx.x + vx.y * vx.y + vx.z * vx.z + vx.w * vx.w;
  float sy = vy.x * vy.x + vy.y * vy.y + vy.z * vy.z + vy.w * vy.w;
  float sxy = vx.x * vy.x + vx.y * vy.y + vx.z * vy.z + vx.w * vy.w;
  #pragma unroll
  for (int off = 32; off; off >>= 1) {
    sx += __shfl_xor(sx, off);
    sy += __shfl_xor(sy, off);
    sxy += __shfl_xor(sxy, off);
  }
  const float scx = LOG2E / fmaxf(sqrtf(sx), 1e-8f);   // log2e folded into A
  const float scy = 1.0f / fmaxf(sqrtf(sy), 1e-8f);
  if (lane == 0) diagF[r] = sxy * (scx / LOG2E) * scy;
  xn8[(size_t)r * 64 + lane] = pack4_e4m3(vx.x * scx, vx.y * scx, vx.z * scx, vx.w * scx);
  // y fragment-major: this lane's 4 bytes cover k = [4*lane, 4*lane+4)
  const unsigned int py = pack4_e4m3(vy.x * scy, vy.y * scy, vy.z * scy, vy.w * scy);
  const int t2 = (r >> 4) * 2 + (lane >> 5);             // global tile*2 + kb
  const int fl = ((lane >> 3) & 3) * 16 + (r & 15);      // fragment lane
  const unsigned dst = (unsigned)t2 * 2048 + (unsigned)fl * 32 + (lane & 7) * 4;
  *reinterpret_cast<unsigned int*>(ybf + dst) = py;
}

// ------------------------------------------------------------------
// Kernel 2: barrier-free, LDS-free MX-fp8 GEMM + exp2.
// R15's proven structure (wave = 64-row band x 1024-col chunk; A in
// regs; B direct global->reg from fragment-major ybf). ONE change:
// after the MFMA convoy consumes b0/b1, re-load them in place with
// tile t+1's fragments BEFORE the epilogue — the ~200-cyc epilogue
// (exp2 + reduce + store) covers the L2 latency. Straight-line code,
// no lambdas (R11/R17 spill pattern), launch_bounds(256,3).
// ------------------------------------------------------------------
__global__ __launch_bounds__(256, 3) void gemm_exp_kernel(
    const unsigned char* __restrict__ xn8, const unsigned char* __restrict__ ybf,
    float* __restrict__ rowpart, float* __restrict__ colpartW,
    float* __restrict__ rowsumG, float* __restrict__ colsumG, int use_scratch) {
  const int tid = threadIdx.x;
  const int lane = tid & 63;
  const int wid = tid >> 6;
  const int grp = lane >> 4, li = lane & 15;

  const int bid = blockIdx.x;                // 0..1023
  const int xcd = bid & 7;
  const int rest = bid >> 3;                 // 0..127
  const int chunk = xcd * 2 + (rest >> 6);   // 0..15 (2 chunks/XCD -> L2)
  const int band = ((rest & 63) << 2) + wid; // 0..255 (64-row band per wave)
  const int rowBase = band * 64;
  const int colBase = chunk * CH;

  // ---- A: 64 rows x 256 K fp8 -> a[4][2] i32x8 (64 VGPR) ----
  i32x8 a[4][2];
  #pragma unroll
  for (int m = 0; m < 4; ++m)
    #pragma unroll
    for (int kb = 0; kb < 2; ++kb) {
      const int row = rowBase + m * 16 + li;
      a[m][kb] = *reinterpret_cast<const i32x8*>(
          xn8 + (size_t)row * DIM + kb * 128 + grp * 32);
    }

  f32x4 rsum4[4];
  #pragma unroll
  for (int m = 0; m < 4; ++m) rsum4[m] = (f32x4)(0.0f);

  const f32x4 z4 = (f32x4)(0.0f);
  // per-lane B pointer: chunk base + lane's 32B fragment slot
  const unsigned char* yb = ybf + (size_t)chunk * (NT * 4096) + (size_t)lane * 32;

  i32x8 b0 = *reinterpret_cast<const i32x8*>(yb);
  i32x8 b1 = *reinterpret_cast<const i32x8*>(yb + 2048);

  for (int t = 0; t < NT; ++t) {
    f32x4 acc[4];
    __builtin_amdgcn_s_setprio(1);
    #pragma unroll
    for (int m = 0; m < 4; ++m)
      acc[m] = __builtin_amdgcn_mfma_scale_f32_16x16x128_f8f6f4(
          a[m][0], b0, z4, 0, 0, 0, 127, 0, 127);
    #pragma unroll
    for (int m = 0; m < 4; ++m)
      acc[m] = __builtin_amdgcn_mfma_scale_f32_16x16x128_f8f6f4(
          a[m][1], b1, acc[m], 0, 0, 0, 127, 0, 127);
    __builtin_amdgcn_s_setprio(0);

    // prefetch tile t+1's B in place: issues now, waits after epilogue
    if (t + 1 < NT) {
      yb += 4096;
      b0 = *reinterpret_cast<const i32x8*>(yb);
      b1 = *reinterpret_cast<const i32x8*>(yb + 2048);
    }

    // ---- epilogue: exp2 + row/col partials [verbatim R15] ----
    float cs = 0.0f;
    #pragma unroll
    for (int m = 0; m < 4; ++m) {
      #pragma unroll
      for (int j = 0; j < 4; ++j) {
        const float e = fexp2(acc[m][j]);
        rsum4[m][j] += e;
        cs += e;
      }
    }
    cs += __shfl_xor(cs, 16);
    cs += __shfl_xor(cs, 32);
    if (grp == 0) {
      const int c = colBase + t * 16 + li;
      if (use_scratch) colpartW[(size_t)band * N_ROWS + c] = cs;
      else atomicAdd(&colsumG[c], cs);
    }
  }

  // ---- row sums: wave-exclusive rows, direct write ----
  #pragma unroll
  for (int m = 0; m < 4; ++m) {
    #pragma unroll
    for (int j = 0; j < 4; ++j) {
      float v = rsum4[m][j];
      v += __shfl_xor(v, 1); v += __shfl_xor(v, 2);
      v += __shfl_xor(v, 4); v += __shfl_xor(v, 8);
      if (li == 0) {
        const int r = rowBase + m * 16 + grp * 4 + j;
        if (use_scratch) rowpart[(size_t)chunk * N_ROWS + r] = v;
        else atomicAdd(&rowsumG[r], v);
      }
    }
  }
}

// ------------------------------------------------------------------
// Kernel 3: reduce partials + final loss. [verbatim R15]
// ------------------------------------------------------------------
__global__ __launch_bounds__(256) void finalize_kernel(
    const float* __restrict__ rowpart, const float* __restrict__ colpartW,
    const float* __restrict__ rowsumG, const float* __restrict__ colsumG,
    const float* __restrict__ diagF, float* __restrict__ out, int use_scratch) {
  __shared__ float red[4];
  const int i = blockIdx.x * 256 + threadIdx.x;
  float rs, cs;
  if (use_scratch) {
    rs = 0.0f;
    #pragma unroll
    for (int c = 0; c < 16; ++c) rs += rowpart[(size_t)c * N_ROWS + i];
    cs = 0.0f;
    #pragma unroll 8
    for (int b = 0; b < 256; ++b) cs += colpartW[(size_t)b * N_ROWS + i];
  } else {
    rs = rowsumG[i];
    cs = colsumG[i];
  }
  const float d = diagF[i];
  const float e8 = fexp2(LOG2E * d);          // ~= gemm's exp2(S'_ii)
  const float mm = __expf(d - MARGINF);
  float v = mm / (mm + rs - e8) + mm / (mm + cs - e8);
  #pragma unroll
  for (int off = 32; off; off >>= 1) v += __shfl_xor(v, off);
  if ((threadIdx.x & 63) == 0) red[threadIdx.x >> 6] = v;
  __syncthreads();
  if (threadIdx.x == 0) {
    const float t = red[0] + red[1] + red[2] + red[3];
    atomicAdd(out, -t / (float)N_ROWS);
  }
}

// ------------------------------------------------------------------
extern "C" void kernel_launch(void* const* d_in, const int* in_sizes, int n_in,
                              void* d_out, int out_size, void* d_ws, size_t ws_size,
                              hipStream_t stream) {
  const float* x = (const float*)d_in[0];
  const float* y = (const float*)d_in[1];
  char* ws = (char*)d_ws;
  unsigned char* xn8 = (unsigned char*)ws;                   // 4 MiB
  unsigned char* ybf = (unsigned char*)(ws + (4u << 20));    // 4 MiB (frag-major)
  float* diagF    = (float*)(ws + (8u << 20));               // 64 KiB
  float* rowpart  = (float*)(ws + (8u << 20) + 65536);       // 1 MiB [16][N]
  float* colpartW = (float*)(ws + (8u << 20) + 65536 + (1u << 20));  // 16 MiB [256][N]
  float* rowsumG = rowpart;                                  // fallback aliases
  float* colsumG = rowpart + N_ROWS;
  const size_t need_scratch = (8u << 20) + 65536 + (1u << 20) + (16u << 20);
  const int use_scratch = (ws_size >= need_scratch) ? 1 : 0;

  hipMemsetAsync(d_out, 0, sizeof(float), stream);
  if (!use_scratch) hipMemsetAsync(rowsumG, 0, 2 * N_ROWS * sizeof(float), stream);
  normalize_kernel<<<4096, 256, 0, stream>>>(x, y, (unsigned int*)xn8, ybf, diagF);
  gemm_exp_kernel<<<1024, 256, 0, stream>>>(xn8, ybf, rowpart, colpartW,
                                            rowsumG, colsumG, use_scratch);
  finalize_kernel<<<64, 256, 0, stream>>>(rowpart, colpartW, rowsumG, colsumG,
                                          diagF, (float*)d_out, use_scratch);
}